// Round 3
// baseline (170.268 us; speedup 1.0000x reference)
//
#include <hip/hip_runtime.h>

typedef unsigned short u16;
typedef float f32x4 __attribute__((ext_vector_type(4)));
typedef short s16x8 __attribute__((ext_vector_type(8)));

#define GPTR(x) ((const __attribute__((address_space(1))) void*)(x))
#define LPTR(x) ((__attribute__((address_space(3))) void*)(x))

__device__ __forceinline__ u16 f32_to_bf16(float f) {
  unsigned u = __builtin_bit_cast(unsigned, f);
  u += 0x7FFFu + ((u >> 16) & 1u);
  return (u16)(u >> 16);
}
__device__ __forceinline__ float bf16_to_f32(u16 h) {
  unsigned u = ((unsigned)h) << 16;
  return __builtin_bit_cast(float, u);
}

// ---------- conversions (vectorized x4) ----------
__global__ void k_cvt4(const float* __restrict__ in, u16* __restrict__ out, int n4) {
  int i = blockIdx.x * 256 + threadIdx.x;
  if (i >= n4) return;
  float4 v = reinterpret_cast<const float4*>(in)[i];
  ushort4 o;
  o.x = f32_to_bf16(v.x); o.y = f32_to_bf16(v.y);
  o.z = f32_to_bf16(v.z); o.w = f32_to_bf16(v.w);
  reinterpret_cast<ushort4*>(out)[i] = o;
}

// mc_text: 1000 rows -> pad to 1024 rows of zeros
__global__ void k_cvt_pad4(const float* __restrict__ in, u16* __restrict__ out, int nreal_rows) {
  int i = blockIdx.x * 256 + threadIdx.x;   // 1024*512/4 elements
  if (i >= 1024 * 128) return;
  int row = (i * 4) >> 9;
  ushort4 o = {0, 0, 0, 0};
  if (row < nreal_rows) {
    float4 v = reinterpret_cast<const float4*>(in)[i];
    o.x = f32_to_bf16(v.x); o.y = f32_to_bf16(v.y);
    o.z = f32_to_bf16(v.z); o.w = f32_to_bf16(v.w);
  }
  reinterpret_cast<ushort4*>(out)[i] = o;
}

// ---------- bf16 GEMM: Cbf[M][N] = bf16( scale * A[M][K=512] * B[N][K]^T ) ----------
// 128x128 tile, 4 waves (2x2), BK=64, XOR-swizzled LDS via pre-swizzled global src +
// global_load_lds width=16 (linear wave-uniform LDS dest).
// COLSUM: also emit per-column partial sums of sigmoid(s) -> colpart[Mblock][2048]
template <bool COLSUM>
__global__ __launch_bounds__(256) void k_gemm_bt(
    const u16* __restrict__ A, const u16* __restrict__ B,
    u16* __restrict__ Cbf, float* __restrict__ colpart, int N, float scale)
{
  constexpr int K = 512;
  constexpr int BK = 64;
  __shared__ __align__(16) u16 As[128 * BK];
  __shared__ __align__(16) u16 Bs[128 * BK];
  const int tid  = threadIdx.x;
  const int lane = tid & 63;
  const int wave = tid >> 6;
  const int wr = wave >> 1, wc = wave & 1;
  const int row0 = blockIdx.x * 128;
  const int col0 = blockIdx.y * 128;

  f32x4 acc[4][4];
#pragma unroll
  for (int i = 0; i < 4; ++i)
#pragma unroll
    for (int j = 0; j < 4; ++j) acc[i][j] = (f32x4){0.f, 0.f, 0.f, 0.f};

  for (int k0 = 0; k0 < K; k0 += BK) {
    __syncthreads();  // protect LDS from previous iteration's reads
    // LDS slot x of row r holds global 16B-chunk (x ^ (r&7)) -> same layout the reads expect
#pragma unroll
    for (int q = 0; q < 4; ++q) {
      int base = wave * 256 + q * 64;      // wave-uniform slot base
      int slot = base + lane;
      int r = slot >> 3, s = slot & 7;
      int sg = s ^ (r & 7);                // pre-swizzled global source chunk
      __builtin_amdgcn_global_load_lds(GPTR(A + (size_t)(row0 + r) * K + k0 + sg * 8),
                                       LPTR(&As[base * 8]), 16, 0, 0);
      __builtin_amdgcn_global_load_lds(GPTR(B + (size_t)(col0 + r) * K + k0 + sg * 8),
                                       LPTR(&Bs[base * 8]), 16, 0, 0);
    }
    __syncthreads();
#pragma unroll
    for (int ks = 0; ks < 2; ++ks) {
      s16x8 af[4], bf[4];
#pragma unroll
      for (int mm = 0; mm < 4; ++mm) {
        int r = wr * 64 + mm * 16 + (lane & 15);
        int ss = (ks * 4 + (lane >> 4)) ^ (r & 7);
        af[mm] = *reinterpret_cast<const s16x8*>(&As[r * BK + ss * 8]);
      }
#pragma unroll
      for (int nn = 0; nn < 4; ++nn) {
        int r = wc * 64 + nn * 16 + (lane & 15);
        int ss = (ks * 4 + (lane >> 4)) ^ (r & 7);
        bf[nn] = *reinterpret_cast<const s16x8*>(&Bs[r * BK + ss * 8]);
      }
#pragma unroll
      for (int mm = 0; mm < 4; ++mm)
#pragma unroll
        for (int nn = 0; nn < 4; ++nn)
          acc[mm][nn] = __builtin_amdgcn_mfma_f32_16x16x32_bf16(af[mm], bf[nn], acc[mm][nn], 0, 0, 0);
    }
  }
  // C/D layout: col = lane&15, row = (lane>>4)*4 + reg
  const int cr = (lane >> 4) * 4;
  const int cc = lane & 15;
#pragma unroll
  for (int mm = 0; mm < 4; ++mm) {
    int orow = row0 + wr * 64 + mm * 16 + cr;
#pragma unroll
    for (int nn = 0; nn < 4; ++nn) {
      int ocol = col0 + wc * 64 + nn * 16 + cc;
#pragma unroll
      for (int r = 0; r < 4; ++r)
        Cbf[(size_t)(orow + r) * N + ocol] = f32_to_bf16(acc[mm][nn][r] * scale);
    }
  }

  if constexpr (COLSUM) {
    __shared__ float cp[128];
    if (tid < 128) cp[tid] = 0.f;
    __syncthreads();
#pragma unroll
    for (int nn = 0; nn < 4; ++nn) {
      float cs = 0.f;
#pragma unroll
      for (int mm = 0; mm < 4; ++mm)
#pragma unroll
        for (int r = 0; r < 4; ++r) {
          float s = acc[mm][nn][r] * scale;
          cs += 1.f / (1.f + __expf(-s));
        }
      cs += __shfl_xor(cs, 16);
      cs += __shfl_xor(cs, 32);
      if (lane < 16) atomicAdd(&cp[wc * 64 + nn * 16 + lane], cs);  // 2 adds/slot: commutative
    }
    __syncthreads();
    if (tid < 128) colpart[(size_t)blockIdx.x * 2048 + col0 + tid] = cp[tid];
  }
}

// ---------- c_jk = b_jk / colsum_k ----------
__global__ void k_reduce_c(const float* __restrict__ part, const float* __restrict__ ratios,
                           float* __restrict__ c) {
  int j = blockIdx.x * 256 + threadIdx.x;  // 2048
  float s = 0.f;
  for (int ch = 0; ch < 64; ++ch) s += part[ch * 2048 + j];
  float b0 = ratios[j] * 8192.f;
  float b1 = (1.f - ratios[j]) * 8192.f;
  c[2 * j]     = b0 / s;
  c[2 * j + 1] = b1 / (8192.f - s);
}

// ---------- ml pass 2: 1024 threads = 4 row-groups x 256 col-threads; 16 rows/block ----------
__global__ __launch_bounds__(1024) void k_ml_pass2(
    const u16* __restrict__ S, const float* __restrict__ T, const float* __restrict__ c,
    float* __restrict__ part2, float* __restrict__ partT, float* __restrict__ partE)
{
  __shared__ float sm[4][2048];
  const int tid = threadIdx.x;
  const int g = tid >> 8;              // row group 0..3
  const int t = tid & 255;             // col group: cols t*8 .. t*8+7
  float c0[8], c1[8];
#pragma unroll
  for (int q = 0; q < 4; ++q) {
    float4 cv = reinterpret_cast<const float4*>(c)[t * 4 + q];
    c0[q * 2]     = cv.x; c1[q * 2]     = cv.y;
    c0[q * 2 + 1] = cv.z; c1[q * 2 + 1] = cv.w;
  }

  float q0s[8], ts[8];
#pragma unroll
  for (int k = 0; k < 8; ++k) { q0s[k] = 0.f; ts[k] = 0.f; }
  float tss = 0.f, ldsum = 0.f;

  const int base = blockIdx.x * 16 + g * 4;
#pragma unroll
  for (int r = 0; r < 4; ++r) {
    size_t row = base + r;
    s16x8 sv = *reinterpret_cast<const s16x8*>(S + row * 2048 + t * 8);
    float4 ta = reinterpret_cast<const float4*>(T + row * 2048)[t * 2];
    float4 tb = reinterpret_cast<const float4*>(T + row * 2048)[t * 2 + 1];
    float tv[8] = {ta.x, ta.y, ta.z, ta.w, tb.x, tb.y, tb.z, tb.w};
#pragma unroll
    for (int k = 0; k < 8; ++k) {
      float s = bf16_to_f32((u16)sv[k]);
      float e = __expf(s);
      float n0 = e * c0[k];
      float den = n0 + c1[k];
      q0s[k] += n0 * __builtin_amdgcn_rcpf(den);
      ldsum  += __logf(den);
      ts[k]  += tv[k];
      tss    += tv[k] * s;
    }
  }
  // es = sum t*s - sum ln(den) + sum_k [ ln(c0/c1)*ts_k + nrows*ln(c1) ]
  float es = tss - ldsum;
#pragma unroll
  for (int k = 0; k < 8; ++k)
    es += __logf(c0[k] / c1[k]) * ts[k] + 4.f * __logf(c1[k]);

  // fold 4 row-groups via LDS
#pragma unroll
  for (int k = 0; k < 8; ++k) sm[g][t * 8 + k] = q0s[k];
  __syncthreads();
  if (g == 0) {
#pragma unroll
    for (int k = 0; k < 8; ++k) {
      int col = t * 8 + k;
      part2[(size_t)blockIdx.x * 2048 + col] = sm[0][col] + sm[1][col] + sm[2][col] + sm[3][col];
    }
  }
  __syncthreads();
#pragma unroll
  for (int k = 0; k < 8; ++k) sm[g][t * 8 + k] = ts[k];
  __syncthreads();
  if (g == 0) {
#pragma unroll
    for (int k = 0; k < 8; ++k) {
      int col = t * 8 + k;
      partT[(size_t)blockIdx.x * 2048 + col] = sm[0][col] + sm[1][col] + sm[2][col] + sm[3][col];
    }
  }
  __syncthreads();
  float* red = &sm[0][0];
  red[tid] = es;
  __syncthreads();
  for (int o = 512; o; o >>= 1) {
    if (tid < o) red[tid] += red[tid + o];
    __syncthreads();
  }
  if (tid == 0) partE[blockIdx.x] = red[0];
}

// ---------- column reduce, stage A: 512 chunks -> 8 ----------
__global__ __launch_bounds__(256) void k_colredA(
    const float* __restrict__ part2, const float* __restrict__ partT,
    float* __restrict__ pA2, float* __restrict__ pAT)
{
  int j = blockIdx.x * 256 + threadIdx.x;  // 2048 cols over 8 x-blocks
  int ch0 = blockIdx.y * 64;
  float cs2 = 0.f, Tj = 0.f;
  for (int ch = ch0; ch < ch0 + 64; ++ch) {
    cs2 += part2[(size_t)ch * 2048 + j];
    Tj  += partT[(size_t)ch * 2048 + j];
  }
  pA2[(size_t)blockIdx.y * 2048 + j] = cs2;
  pAT[(size_t)blockIdx.y * 2048 + j] = Tj;
}

// ---------- column reduce, stage B: logs + per-column d-term ----------
__global__ __launch_bounds__(256) void k_colredB(
    const float* __restrict__ pA2, const float* __restrict__ pAT,
    const float* __restrict__ ratios, float* __restrict__ partCol)
{
  int j = blockIdx.x * 256 + threadIdx.x;  // 2048
  float cs2 = 0.f, Tj = 0.f;
  for (int ch = 0; ch < 8; ++ch) {
    cs2 += pA2[(size_t)ch * 2048 + j];
    Tj  += pAT[(size_t)ch * 2048 + j];
  }
  float b0 = ratios[j] * 8192.f;
  float b1 = (1.f - ratios[j]) * 8192.f;
  float colp = Tj * __logf(b0 / cs2) + (8192.f - Tj) * __logf(b1 / (8192.f - cs2));
  __shared__ float red[256];
  red[threadIdx.x] = colp;
  __syncthreads();
  for (int o = 128; o; o >>= 1) {
    if (threadIdx.x < o) red[threadIdx.x] += red[threadIdx.x + o];
    __syncthreads();
  }
  if (threadIdx.x == 0) partCol[blockIdx.x] = red[0];
}

// ---------- mc rows: R_i, rowdot_i, trow_i (bf16 S, vectorized) ----------
__global__ __launch_bounds__(256) void k_mc_rows(
    const u16* __restrict__ S2, const float* __restrict__ T2,
    float* __restrict__ R, float* __restrict__ rowdot, float* __restrict__ trow)
{
  int wave = threadIdx.x >> 6, lane = threadIdx.x & 63;
  int row = blockIdx.x * 4 + wave;
  const u16* s = S2 + (size_t)row * 1024;
  const float* t = T2 + (size_t)row * 1000;
  float re = 0.f, rd = 0.f, tr = 0.f;
#pragma unroll
  for (int g0 = 0; g0 < 2; ++g0) {
    int g = lane + g0 * 64;
    if (g < 125) {
      s16x8 sv = *reinterpret_cast<const s16x8*>(s + g * 8);
      float4 ta = reinterpret_cast<const float4*>(t)[g * 2];
      float4 tb = reinterpret_cast<const float4*>(t)[g * 2 + 1];
      float tv[8] = {ta.x, ta.y, ta.z, ta.w, tb.x, tb.y, tb.z, tb.w};
#pragma unroll
      for (int k = 0; k < 8; ++k) {
        float sf = bf16_to_f32((u16)sv[k]);
        re += __expf(sf);
        rd += tv[k] * sf;
        tr += tv[k];
      }
    }
  }
#pragma unroll
  for (int o = 32; o; o >>= 1) {
    re += __shfl_down(re, o);
    rd += __shfl_down(rd, o);
    tr += __shfl_down(tr, o);
  }
  if (lane == 0) { R[row] = re; rowdot[row] = rd; trow[row] = tr; }
}

// ---------- finalize ----------
__global__ __launch_bounds__(1024) void k_finalize(
    const float* __restrict__ R, const float* __restrict__ rowdot, const float* __restrict__ trow,
    const int* __restrict__ ds,
    const float* __restrict__ partE, const float* __restrict__ partCol,
    float* __restrict__ out)
{
  __shared__ float red[1024];
  const int tid = threadIdx.x;

  auto bsum = [&](float v) -> float {
    __syncthreads();
    red[tid] = v;
    __syncthreads();
    for (int o = 512; o; o >>= 1) {
      if (tid < o) red[tid] += red[tid + o];
      __syncthreads();
    }
    return red[0];
  };

  float nmc = 0.f, nml = 0.f;
  for (int i = tid; i < 8192; i += 1024) {
    int d = ds[i];
    nmc += (d == 1) ? 1.f : 0.f;
    nml += (d == 0) ? 1.f : 0.f;
  }
  float n_mc = bsum(nmc);
  float n_ml = bsum(nml);
  float m = n_mc + 0.1f * n_ml;

  float a[8], Rv[8];
#pragma unroll
  for (int q = 0; q < 8; ++q) { Rv[q] = R[tid + q * 1024]; a[q] = 1.f; }
  for (int it = 0; it < 5; ++it) {
    float p = 0.f;
#pragma unroll
    for (int q = 0; q < 8; ++q) {
      a[q] = a[q] / fmaxf(Rv[q] * a[q], 1.f);
      p += Rv[q] * a[q];
    }
    float tot = bsum(p);
    float sc = m / tot;
#pragma unroll
    for (int q = 0; q < 8; ++q) a[q] *= sc;
  }
  float mcp = 0.f;
#pragma unroll
  for (int q = 0; q < 8; ++q) {
    int i = tid + q * 1024;
    mcp += rowdot[i] + trow[i] * __logf(a[q]);
  }

  float ep = 0.f;
  for (int k = tid; k < 512; k += 1024) ep += partE[k];
  float cp = 0.f;
  if (tid < 8) cp = partCol[tid];

  float total = bsum(-mcp - 0.5f * (cp + ep));
  if (tid == 0) out[0] = total;
}

extern "C" void kernel_launch(void* const* d_in, const int* in_sizes, int n_in,
                              void* d_out, int out_size, void* d_ws, size_t ws_size,
                              hipStream_t stream)
{
  const float* features = (const float*)d_in[0];  // [8192][512]
  const float* ml_text  = (const float*)d_in[1];  // [2048][512]
  const float* mc_text  = (const float*)d_in[2];  // [1000][512]
  const float* ml_tgt   = (const float*)d_in[3];  // [8192][2048]
  const float* mc_tgt   = (const float*)d_in[4];  // [8192][1000]
  const int*   dsidx    = (const int*)d_in[5];    // [8192]
  const float* ratios   = (const float*)d_in[6];  // [2048]
  float* out = (float*)d_out;

  char* ws = (char*)d_ws;
  size_t off = 0;
  auto alloc = [&](size_t bytes) -> void* {
    void* p = ws + off;
    off += (bytes + 255) & ~(size_t)255;
    return p;
  };
  u16*   Abf    = (u16*)alloc((size_t)8192 * 512 * 2);
  u16*   MLbf   = (u16*)alloc((size_t)2048 * 512 * 2);
  u16*   MCbf   = (u16*)alloc((size_t)1024 * 512 * 2);
  u16*   Sml    = (u16*)alloc((size_t)8192 * 2048 * 2);
  u16*   Smc    = (u16*)alloc((size_t)8192 * 1024 * 2);
  float* part1  = (float*)alloc((size_t)64 * 2048 * 4);
  float* cbuf   = (float*)alloc((size_t)2048 * 2 * 4);
  float* part2  = (float*)alloc((size_t)512 * 2048 * 4);
  float* partT  = (float*)alloc((size_t)512 * 2048 * 4);
  float* pA2    = (float*)alloc((size_t)8 * 2048 * 4);
  float* pAT    = (float*)alloc((size_t)8 * 2048 * 4);
  float* partE  = (float*)alloc((size_t)512 * 4);
  float* partCol= (float*)alloc((size_t)8 * 4);
  float* Rbuf   = (float*)alloc((size_t)8192 * 4);
  float* rdot   = (float*)alloc((size_t)8192 * 4);
  float* trow   = (float*)alloc((size_t)8192 * 4);

  k_cvt4<<<(8192 * 128 + 255) / 256, 256, 0, stream>>>(features, Abf, 8192 * 128);
  k_cvt4<<<(2048 * 128 + 255) / 256, 256, 0, stream>>>(ml_text, MLbf, 2048 * 128);
  k_cvt_pad4<<<(1024 * 128 + 255) / 256, 256, 0, stream>>>(mc_text, MCbf, 1000);

  const float scale = 1.0f / 0.07f;
  k_gemm_bt<true ><<<dim3(64, 16), 256, 0, stream>>>(Abf, MLbf, Sml, part1, 2048, scale);
  k_gemm_bt<false><<<dim3(64, 8),  256, 0, stream>>>(Abf, MCbf, Smc, nullptr, 1024, scale);

  k_reduce_c<<<8, 256, 0, stream>>>(part1, ratios, cbuf);
  k_ml_pass2<<<512, 1024, 0, stream>>>(Sml, ml_tgt, cbuf, part2, partT, partE);
  k_mc_rows<<<2048, 256, 0, stream>>>(Smc, mc_tgt, Rbuf, rdot, trow);
  k_colredA<<<dim3(8, 8), 256, 0, stream>>>(part2, partT, pA2, pAT);
  k_colredB<<<8, 256, 0, stream>>>(pA2, pAT, ratios, partCol);
  k_finalize<<<1, 1024, 0, stream>>>(Rbuf, rdot, trow, dsidx, partE, partCol, out);
}

// Round 4
// 130.699 us; speedup vs baseline: 1.3027x; 1.3027x over previous
//
#include <hip/hip_runtime.h>

typedef unsigned short u16;
typedef float f32x4 __attribute__((ext_vector_type(4)));
typedef short s16x8 __attribute__((ext_vector_type(8)));

#define GPTR(x) ((const __attribute__((address_space(1))) void*)(x))
#define LPTR(x) ((__attribute__((address_space(3))) void*)(x))

__device__ __forceinline__ u16 f32_to_bf16(float f) {
  unsigned u = __builtin_bit_cast(unsigned, f);
  u += 0x7FFFu + ((u >> 16) & 1u);
  return (u16)(u >> 16);
}
__device__ __forceinline__ float bf16_to_f32(u16 h) {
  unsigned u = ((unsigned)h) << 16;
  return __builtin_bit_cast(float, u);
}

// ---------- conversions (vectorized x4) ----------
__global__ void k_cvt4(const float* __restrict__ in, u16* __restrict__ out, int n4) {
  int i = blockIdx.x * 256 + threadIdx.x;
  if (i >= n4) return;
  float4 v = reinterpret_cast<const float4*>(in)[i];
  ushort4 o;
  o.x = f32_to_bf16(v.x); o.y = f32_to_bf16(v.y);
  o.z = f32_to_bf16(v.z); o.w = f32_to_bf16(v.w);
  reinterpret_cast<ushort4*>(out)[i] = o;
}

// mc_text: 1000 rows -> pad to 1024 rows of zeros
__global__ void k_cvt_pad4(const float* __restrict__ in, u16* __restrict__ out, int nreal_rows) {
  int i = blockIdx.x * 256 + threadIdx.x;   // 1024*512/4 elements
  if (i >= 1024 * 128) return;
  int row = (i * 4) >> 9;
  ushort4 o = {0, 0, 0, 0};
  if (row < nreal_rows) {
    float4 v = reinterpret_cast<const float4*>(in)[i];
    o.x = f32_to_bf16(v.x); o.y = f32_to_bf16(v.y);
    o.z = f32_to_bf16(v.z); o.w = f32_to_bf16(v.w);
  }
  reinterpret_cast<ushort4*>(out)[i] = o;
}

// ---------- bf16 GEMM: Cbf[M][N] = bf16( scale * A[M][K=512] * B[N][K]^T ) ----------
// 128x128 tile, 4 waves (2x2), BK=64, XOR-swizzled LDS via pre-swizzled global src +
// global_load_lds width=16 (linear wave-uniform LDS dest).
// COLSUM: also emit per-column partial sums of sigmoid(s) -> colpart[Mblock][2048]
template <bool COLSUM>
__global__ __launch_bounds__(256) void k_gemm_bt(
    const u16* __restrict__ A, const u16* __restrict__ B,
    u16* __restrict__ Cbf, float* __restrict__ colpart, int N, float scale)
{
  constexpr int K = 512;
  constexpr int BK = 64;
  __shared__ __align__(16) u16 As[128 * BK];
  __shared__ __align__(16) u16 Bs[128 * BK];
  const int tid  = threadIdx.x;
  const int lane = tid & 63;
  const int wave = tid >> 6;
  const int wr = wave >> 1, wc = wave & 1;
  const int row0 = blockIdx.x * 128;
  const int col0 = blockIdx.y * 128;

  f32x4 acc[4][4];
#pragma unroll
  for (int i = 0; i < 4; ++i)
#pragma unroll
    for (int j = 0; j < 4; ++j) acc[i][j] = (f32x4){0.f, 0.f, 0.f, 0.f};

  for (int k0 = 0; k0 < K; k0 += BK) {
    __syncthreads();  // protect LDS from previous iteration's reads
    // LDS slot x of row r holds global 16B-chunk (x ^ (r&7)) -> same layout the reads expect
#pragma unroll
    for (int q = 0; q < 4; ++q) {
      int base = wave * 256 + q * 64;      // wave-uniform slot base
      int slot = base + lane;
      int r = slot >> 3, s = slot & 7;
      int sg = s ^ (r & 7);                // pre-swizzled global source chunk
      __builtin_amdgcn_global_load_lds(GPTR(A + (size_t)(row0 + r) * K + k0 + sg * 8),
                                       LPTR(&As[base * 8]), 16, 0, 0);
      __builtin_amdgcn_global_load_lds(GPTR(B + (size_t)(col0 + r) * K + k0 + sg * 8),
                                       LPTR(&Bs[base * 8]), 16, 0, 0);
    }
    __syncthreads();
#pragma unroll
    for (int ks = 0; ks < 2; ++ks) {
      s16x8 af[4], bf[4];
#pragma unroll
      for (int mm = 0; mm < 4; ++mm) {
        int r = wr * 64 + mm * 16 + (lane & 15);
        int ss = (ks * 4 + (lane >> 4)) ^ (r & 7);
        af[mm] = *reinterpret_cast<const s16x8*>(&As[r * BK + ss * 8]);
      }
#pragma unroll
      for (int nn = 0; nn < 4; ++nn) {
        int r = wc * 64 + nn * 16 + (lane & 15);
        int ss = (ks * 4 + (lane >> 4)) ^ (r & 7);
        bf[nn] = *reinterpret_cast<const s16x8*>(&Bs[r * BK + ss * 8]);
      }
#pragma unroll
      for (int mm = 0; mm < 4; ++mm)
#pragma unroll
        for (int nn = 0; nn < 4; ++nn)
          acc[mm][nn] = __builtin_amdgcn_mfma_f32_16x16x32_bf16(af[mm], bf[nn], acc[mm][nn], 0, 0, 0);
    }
  }
  // C/D layout: col = lane&15, row = (lane>>4)*4 + reg
  const int cr = (lane >> 4) * 4;
  const int cc = lane & 15;
#pragma unroll
  for (int mm = 0; mm < 4; ++mm) {
    int orow = row0 + wr * 64 + mm * 16 + cr;
#pragma unroll
    for (int nn = 0; nn < 4; ++nn) {
      int ocol = col0 + wc * 64 + nn * 16 + cc;
#pragma unroll
      for (int r = 0; r < 4; ++r)
        Cbf[(size_t)(orow + r) * N + ocol] = f32_to_bf16(acc[mm][nn][r] * scale);
    }
  }

  if constexpr (COLSUM) {
    __shared__ float cp[128];
    if (tid < 128) cp[tid] = 0.f;
    __syncthreads();
#pragma unroll
    for (int nn = 0; nn < 4; ++nn) {
      float cs = 0.f;
#pragma unroll
      for (int mm = 0; mm < 4; ++mm)
#pragma unroll
        for (int r = 0; r < 4; ++r) {
          float s = acc[mm][nn][r] * scale;
          cs += 1.f / (1.f + __expf(-s));
        }
      cs += __shfl_xor(cs, 16);
      cs += __shfl_xor(cs, 32);
      if (lane < 16) atomicAdd(&cp[wc * 64 + nn * 16 + lane], cs);  // 2 adds/slot: commutative
    }
    __syncthreads();
    if (tid < 128) colpart[(size_t)blockIdx.x * 2048 + col0 + tid] = cp[tid];
  }
}

// ---------- c_jk = b_jk / colsum_k ----------
__global__ void k_reduce_c(const float* __restrict__ part, const float* __restrict__ ratios,
                           float* __restrict__ c) {
  int j = blockIdx.x * 256 + threadIdx.x;  // 2048
  float s = 0.f;
  for (int ch = 0; ch < 64; ++ch) s += part[ch * 2048 + j];
  float b0 = ratios[j] * 8192.f;
  float b1 = (1.f - ratios[j]) * 8192.f;
  c[2 * j]     = b0 / s;
  c[2 * j + 1] = b1 / (8192.f - s);
}

// ---------- ml pass 2: 1024 blocks x 256 threads; 8 rows x 8 cols per thread ----------
__global__ __launch_bounds__(256) void k_ml_pass2(
    const u16* __restrict__ S, const float* __restrict__ T, const float* __restrict__ c,
    float* __restrict__ part2, float* __restrict__ partT, float* __restrict__ partE)
{
  const int t = threadIdx.x;           // col group: cols t*8 .. t*8+7
  const int r0 = blockIdx.x * 8;       // 1024 blocks
  float c0[8], c1[8];
#pragma unroll
  for (int q = 0; q < 4; ++q) {
    float4 cv = reinterpret_cast<const float4*>(c)[t * 4 + q];
    c0[q * 2]     = cv.x; c1[q * 2]     = cv.y;
    c0[q * 2 + 1] = cv.z; c1[q * 2 + 1] = cv.w;
  }

  float q0s[8], ts[8];
#pragma unroll
  for (int k = 0; k < 8; ++k) { q0s[k] = 0.f; ts[k] = 0.f; }
  float tss = 0.f, ldsum = 0.f;

#pragma unroll 2
  for (int r = 0; r < 8; ++r) {
    size_t row = r0 + r;
    s16x8 sv = *reinterpret_cast<const s16x8*>(S + row * 2048 + t * 8);
    float4 ta = reinterpret_cast<const float4*>(T + row * 2048)[t * 2];
    float4 tb = reinterpret_cast<const float4*>(T + row * 2048)[t * 2 + 1];
    float tv[8] = {ta.x, ta.y, ta.z, ta.w, tb.x, tb.y, tb.z, tb.w};
#pragma unroll
    for (int k = 0; k < 8; ++k) {
      float s = bf16_to_f32((u16)sv[k]);
      float e = __expf(s);
      float n0 = e * c0[k];
      float den = n0 + c1[k];
      q0s[k] += n0 * __builtin_amdgcn_rcpf(den);
      ldsum  += __logf(den);
      ts[k]  += tv[k];
      tss    += tv[k] * s;
    }
  }
  // es = sum t*s - sum ln(den) + sum_k [ ln(c0/c1)*ts_k + nrows*ln(c1) ]
  float es = tss - ldsum;
#pragma unroll
  for (int k = 0; k < 8; ++k)
    es += __logf(c0[k] / c1[k]) * ts[k] + 8.f * __logf(c1[k]);

  // vectorized partial stores (each thread owns its 8 cols exclusively)
  float* p2 = part2 + (size_t)blockIdx.x * 2048 + t * 8;
  float* pT = partT + (size_t)blockIdx.x * 2048 + t * 8;
#pragma unroll
  for (int q = 0; q < 2; ++q) {
    reinterpret_cast<float4*>(p2)[q] = (float4){q0s[q*4], q0s[q*4+1], q0s[q*4+2], q0s[q*4+3]};
    reinterpret_cast<float4*>(pT)[q] = (float4){ts[q*4], ts[q*4+1], ts[q*4+2], ts[q*4+3]};
  }

  __shared__ float red[256];
  red[t] = es;
  __syncthreads();
  for (int o = 128; o; o >>= 1) {
    if (t < o) red[t] += red[t + o];
    __syncthreads();
  }
  if (t == 0) partE[blockIdx.x] = red[0];
}

// ---------- column reduce, stage A: 1024 chunks -> 8 ----------
__global__ __launch_bounds__(256) void k_colredA(
    const float* __restrict__ part2, const float* __restrict__ partT,
    float* __restrict__ pA2, float* __restrict__ pAT)
{
  int j = blockIdx.x * 256 + threadIdx.x;  // 2048 cols over 8 x-blocks
  int ch0 = blockIdx.y * 128;
  float cs2 = 0.f, Tj = 0.f;
  for (int ch = ch0; ch < ch0 + 128; ++ch) {
    cs2 += part2[(size_t)ch * 2048 + j];
    Tj  += partT[(size_t)ch * 2048 + j];
  }
  pA2[(size_t)blockIdx.y * 2048 + j] = cs2;
  pAT[(size_t)blockIdx.y * 2048 + j] = Tj;
}

// ---------- column reduce, stage B: logs + per-column d-term ----------
__global__ __launch_bounds__(256) void k_colredB(
    const float* __restrict__ pA2, const float* __restrict__ pAT,
    const float* __restrict__ ratios, float* __restrict__ partCol)
{
  int j = blockIdx.x * 256 + threadIdx.x;  // 2048
  float cs2 = 0.f, Tj = 0.f;
  for (int ch = 0; ch < 8; ++ch) {
    cs2 += pA2[(size_t)ch * 2048 + j];
    Tj  += pAT[(size_t)ch * 2048 + j];
  }
  float b0 = ratios[j] * 8192.f;
  float b1 = (1.f - ratios[j]) * 8192.f;
  float colp = Tj * __logf(b0 / cs2) + (8192.f - Tj) * __logf(b1 / (8192.f - cs2));
  __shared__ float red[256];
  red[threadIdx.x] = colp;
  __syncthreads();
  for (int o = 128; o; o >>= 1) {
    if (threadIdx.x < o) red[threadIdx.x] += red[threadIdx.x + o];
    __syncthreads();
  }
  if (threadIdx.x == 0) partCol[blockIdx.x] = red[0];
}

// ---------- mc rows: R_i, rowdot_i, trow_i (bf16 S, vectorized) ----------
__global__ __launch_bounds__(256) void k_mc_rows(
    const u16* __restrict__ S2, const float* __restrict__ T2,
    float* __restrict__ R, float* __restrict__ rowdot, float* __restrict__ trow)
{
  int wave = threadIdx.x >> 6, lane = threadIdx.x & 63;
  int row = blockIdx.x * 4 + wave;
  const u16* s = S2 + (size_t)row * 1024;
  const float* t = T2 + (size_t)row * 1000;
  float re = 0.f, rd = 0.f, tr = 0.f;
#pragma unroll
  for (int g0 = 0; g0 < 2; ++g0) {
    int g = lane + g0 * 64;
    if (g < 125) {
      s16x8 sv = *reinterpret_cast<const s16x8*>(s + g * 8);
      float4 ta = reinterpret_cast<const float4*>(t)[g * 2];
      float4 tb = reinterpret_cast<const float4*>(t)[g * 2 + 1];
      float tv[8] = {ta.x, ta.y, ta.z, ta.w, tb.x, tb.y, tb.z, tb.w};
#pragma unroll
      for (int k = 0; k < 8; ++k) {
        float sf = bf16_to_f32((u16)sv[k]);
        re += __expf(sf);
        rd += tv[k] * sf;
        tr += tv[k];
      }
    }
  }
#pragma unroll
  for (int o = 32; o; o >>= 1) {
    re += __shfl_down(re, o);
    rd += __shfl_down(rd, o);
    tr += __shfl_down(tr, o);
  }
  if (lane == 0) { R[row] = re; rowdot[row] = rd; trow[row] = tr; }
}

// ---------- finalize ----------
__global__ __launch_bounds__(1024) void k_finalize(
    const float* __restrict__ R, const float* __restrict__ rowdot, const float* __restrict__ trow,
    const int* __restrict__ ds,
    const float* __restrict__ partE, const float* __restrict__ partCol,
    float* __restrict__ out)
{
  __shared__ float red[1024];
  const int tid = threadIdx.x;

  auto bsum = [&](float v) -> float {
    __syncthreads();
    red[tid] = v;
    __syncthreads();
    for (int o = 512; o; o >>= 1) {
      if (tid < o) red[tid] += red[tid + o];
      __syncthreads();
    }
    return red[0];
  };

  float nmc = 0.f, nml = 0.f;
  for (int i = tid; i < 8192; i += 1024) {
    int d = ds[i];
    nmc += (d == 1) ? 1.f : 0.f;
    nml += (d == 0) ? 1.f : 0.f;
  }
  float n_mc = bsum(nmc);
  float n_ml = bsum(nml);
  float m = n_mc + 0.1f * n_ml;

  float a[8], Rv[8];
#pragma unroll
  for (int q = 0; q < 8; ++q) { Rv[q] = R[tid + q * 1024]; a[q] = 1.f; }
  for (int it = 0; it < 5; ++it) {
    float p = 0.f;
#pragma unroll
    for (int q = 0; q < 8; ++q) {
      a[q] = a[q] / fmaxf(Rv[q] * a[q], 1.f);
      p += Rv[q] * a[q];
    }
    float tot = bsum(p);
    float sc = m / tot;
#pragma unroll
    for (int q = 0; q < 8; ++q) a[q] *= sc;
  }
  float mcp = 0.f;
#pragma unroll
  for (int q = 0; q < 8; ++q) {
    int i = tid + q * 1024;
    mcp += rowdot[i] + trow[i] * __logf(a[q]);
  }

  float ep = partE[tid];
  float cp = 0.f;
  if (tid < 8) cp = partCol[tid];

  float total = bsum(-mcp - 0.5f * (cp + ep));
  if (tid == 0) out[0] = total;
}

extern "C" void kernel_launch(void* const* d_in, const int* in_sizes, int n_in,
                              void* d_out, int out_size, void* d_ws, size_t ws_size,
                              hipStream_t stream)
{
  const float* features = (const float*)d_in[0];  // [8192][512]
  const float* ml_text  = (const float*)d_in[1];  // [2048][512]
  const float* mc_text  = (const float*)d_in[2];  // [1000][512]
  const float* ml_tgt   = (const float*)d_in[3];  // [8192][2048]
  const float* mc_tgt   = (const float*)d_in[4];  // [8192][1000]
  const int*   dsidx    = (const int*)d_in[5];    // [8192]
  const float* ratios   = (const float*)d_in[6];  // [2048]
  float* out = (float*)d_out;

  char* ws = (char*)d_ws;
  size_t off = 0;
  auto alloc = [&](size_t bytes) -> void* {
    void* p = ws + off;
    off += (bytes + 255) & ~(size_t)255;
    return p;
  };
  u16*   Abf    = (u16*)alloc((size_t)8192 * 512 * 2);
  u16*   MLbf   = (u16*)alloc((size_t)2048 * 512 * 2);
  u16*   MCbf   = (u16*)alloc((size_t)1024 * 512 * 2);
  u16*   Sml    = (u16*)alloc((size_t)8192 * 2048 * 2);
  u16*   Smc    = (u16*)alloc((size_t)8192 * 1024 * 2);
  float* part1  = (float*)alloc((size_t)64 * 2048 * 4);
  float* cbuf   = (float*)alloc((size_t)2048 * 2 * 4);
  float* part2  = (float*)alloc((size_t)1024 * 2048 * 4);
  float* partT  = (float*)alloc((size_t)1024 * 2048 * 4);
  float* pA2    = (float*)alloc((size_t)8 * 2048 * 4);
  float* pAT    = (float*)alloc((size_t)8 * 2048 * 4);
  float* partE  = (float*)alloc((size_t)1024 * 4);
  float* partCol= (float*)alloc((size_t)8 * 4);
  float* Rbuf   = (float*)alloc((size_t)8192 * 4);
  float* rdot   = (float*)alloc((size_t)8192 * 4);
  float* trow   = (float*)alloc((size_t)8192 * 4);

  k_cvt4<<<(8192 * 128 + 255) / 256, 256, 0, stream>>>(features, Abf, 8192 * 128);
  k_cvt4<<<(2048 * 128 + 255) / 256, 256, 0, stream>>>(ml_text, MLbf, 2048 * 128);
  k_cvt_pad4<<<(1024 * 128 + 255) / 256, 256, 0, stream>>>(mc_text, MCbf, 1000);

  const float scale = 1.0f / 0.07f;
  k_gemm_bt<true ><<<dim3(64, 16), 256, 0, stream>>>(Abf, MLbf, Sml, part1, 2048, scale);
  k_gemm_bt<false><<<dim3(64, 8),  256, 0, stream>>>(Abf, MCbf, Smc, nullptr, 1024, scale);

  k_reduce_c<<<8, 256, 0, stream>>>(part1, ratios, cbuf);
  k_ml_pass2<<<1024, 256, 0, stream>>>(Sml, ml_tgt, cbuf, part2, partT, partE);
  k_mc_rows<<<2048, 256, 0, stream>>>(Smc, mc_tgt, Rbuf, rdot, trow);
  k_colredA<<<dim3(8, 8), 256, 0, stream>>>(part2, partT, pA2, pAT);
  k_colredB<<<8, 256, 0, stream>>>(pA2, pAT, ratios, partCol);
  k_finalize<<<1, 1024, 0, stream>>>(Rbuf, rdot, trow, dsidx, partE, partCol, out);
}